// Round 1
// baseline (4100.651 us; speedup 1.0000x reference)
//
#include <hip/hip_runtime.h>

// Problem constants
#define CIN   16
#define TIN   48
#define HD    256
#define G4    1024
#define TOUT  24
#define COUT  8
#define MROWS 16           // batch rows per block
#define NB    8192

// Workspace layout (float offsets)
#define OFF_WTPE  0                         // [256][1024] permuted enc_Whh^T
#define OFF_WTPD  262144                    // [256][1024] permuted dec_Whh^T
#define OFF_WTPIH 524288                    // [16][1024]  permuted enc_Wih^T
#define OFF_BPE   540672                    // [1024] permuted enc bias
#define OFF_BPD   541696                    // [1024] permuted dec bias
#define PREP_TOTAL 542720

// Permutation: WTP[jp*1024 + j*4 + k] = W[(k*256+j)*K + jp]
// so thread tid's float4 at (jp, 4*tid) = the (i,f,g,o) weights of hidden
// unit j=tid against input element jp.

__global__ void prep_kernel(const float* __restrict__ enc_Wih,
                            const float* __restrict__ enc_Whh,
                            const float* __restrict__ enc_b,
                            const float* __restrict__ dec_Whh,
                            const float* __restrict__ dec_b,
                            float* __restrict__ ws)
{
    int p = blockIdx.x * blockDim.x + threadIdx.x;
    if (p >= PREP_TOTAL) return;
    if (p < OFF_WTPD) {
        int q = p;              int jp = q >> 10; int r = q & 1023; int j = r >> 2; int k = r & 3;
        ws[p] = enc_Whh[(k * HD + j) * HD + jp];
    } else if (p < OFF_WTPIH) {
        int q = p - OFF_WTPD;   int jp = q >> 10; int r = q & 1023; int j = r >> 2; int k = r & 3;
        ws[p] = dec_Whh[(k * HD + j) * HD + jp];
    } else if (p < OFF_BPE) {
        int q = p - OFF_WTPIH;  int c = q >> 10;  int r = q & 1023; int j = r >> 2; int k = r & 3;
        ws[p] = enc_Wih[(k * HD + j) * CIN + c];
    } else if (p < OFF_BPD) {
        int q = p - OFF_BPE;    int j = q >> 2;   int k = q & 3;
        ws[p] = enc_b[k * HD + j];
    } else {
        int q = p - OFF_BPD;    int j = q >> 2;   int k = q & 3;
        ws[p] = dec_b[k * HD + j];
    }
}

__device__ __forceinline__ float sigm(float v) {
    return __builtin_amdgcn_rcpf(1.0f + __expf(-v));
}
__device__ __forceinline__ float tanh_f(float v) {
    // tanh(v) = 1 - 2/(1+e^{2v}); robust at +/-inf via v_rcp(inf)=0
    return 1.0f - 2.0f * __builtin_amdgcn_rcpf(1.0f + __expf(2.0f * v));
}

#define FMA4(a, s, w) { (a).x = fmaf((s), (w).x, (a).x); (a).y = fmaf((s), (w).y, (a).y); \
                        (a).z = fmaf((s), (w).z, (a).z); (a).w = fmaf((s), (w).w, (a).w); }

__global__ __launch_bounds__(256, 2) void seq2seq_main(
    const float* __restrict__ x,
    const float* __restrict__ ws,
    const float* __restrict__ denseW,
    const float* __restrict__ denseb,
    float* __restrict__ out)
{
    __shared__ float xs[MROWS * CIN * TIN];   // [m][c][t], 48 KB, contiguous copy of 16 rows
    __shared__ float hT[HD * MROWS];          // [j][m], 16 KB

    const int tid = threadIdx.x;
    const int n0  = blockIdx.x * MROWS;

    // ---- preload this block's x slice (fully contiguous: 12288 floats) ----
    {
        const float4* xg  = (const float4*)(x + (size_t)n0 * (CIN * TIN));
        float4* xs4 = (float4*)xs;
        #pragma unroll
        for (int i = 0; i < (MROWS * CIN * TIN / 4) / 256; ++i)
            xs4[tid + i * 256] = xg[tid + i * 256];
    }
    for (int i = tid; i < HD * MROWS; i += 256) hT[i] = 0.0f;

    float c_reg[MROWS];
    #pragma unroll
    for (int m = 0; m < MROWS; ++m) c_reg[m] = 0.0f;

    const float4 be = *(const float4*)(ws + OFF_BPE + 4 * tid);
    const float4 bd = *(const float4*)(ws + OFF_BPD + 4 * tid);
    const float* WTPe  = ws + OFF_WTPE;
    const float* WTPd  = ws + OFF_WTPD;
    const float* WTPih = ws + OFF_WTPIH;

    __syncthreads();

    // ================= encoder: 48 steps =================
    for (int t = 0; t < TIN; ++t) {
        float4 acc[MROWS];
        #pragma unroll
        for (int m = 0; m < MROWS; ++m) acc[m] = be;

        // x contribution: K = 16
        for (int c = 0; c < CIN; ++c) {
            float4 w = *(const float4*)(WTPih + (c << 10) + (tid << 2));
            #pragma unroll
            for (int m = 0; m < MROWS; ++m) {
                float xv = xs[m * (CIN * TIN) + c * TIN + t];
                FMA4(acc[m], xv, w);
            }
        }
        // h contribution: K = 256
        for (int j = 0; j < HD; ++j) {
            float4 w = *(const float4*)(WTPe + (j << 10) + (tid << 2));
            const float4* hrow = (const float4*)(hT + j * MROWS);
            float4 h0 = hrow[0], h1 = hrow[1], h2 = hrow[2], h3 = hrow[3];
            FMA4(acc[0],  h0.x, w); FMA4(acc[1],  h0.y, w); FMA4(acc[2],  h0.z, w); FMA4(acc[3],  h0.w, w);
            FMA4(acc[4],  h1.x, w); FMA4(acc[5],  h1.y, w); FMA4(acc[6],  h1.z, w); FMA4(acc[7],  h1.w, w);
            FMA4(acc[8],  h2.x, w); FMA4(acc[9],  h2.y, w); FMA4(acc[10], h2.z, w); FMA4(acc[11], h2.w, w);
            FMA4(acc[12], h3.x, w); FMA4(acc[13], h3.y, w); FMA4(acc[14], h3.z, w); FMA4(acc[15], h3.w, w);
        }
        __syncthreads();   // all hT reads done
        // pointwise LSTM update; thread tid owns hidden unit j=tid, acc[m]=(i,f,g,o)
        float hn[MROWS];
        #pragma unroll
        for (int m = 0; m < MROWS; ++m) {
            float iv = sigm(acc[m].x);
            float fv = sigm(acc[m].y);
            float gv = tanh_f(acc[m].z);
            float ov = sigm(acc[m].w);
            float cn = fmaf(fv, c_reg[m], iv * gv);
            c_reg[m] = cn;
            hn[m] = ov * tanh_f(cn);
        }
        {
            float4* dst = (float4*)(hT + tid * MROWS);
            dst[0] = make_float4(hn[0],  hn[1],  hn[2],  hn[3]);
            dst[1] = make_float4(hn[4],  hn[5],  hn[6],  hn[7]);
            dst[2] = make_float4(hn[8],  hn[9],  hn[10], hn[11]);
            dst[3] = make_float4(hn[12], hn[13], hn[14], hn[15]);
        }
        __syncthreads();
    }

    // ================= decoder: 24 steps (zero input, c resets to 0) =================
    #pragma unroll
    for (int m = 0; m < MROWS; ++m) c_reg[m] = 0.0f;

    for (int t = 0; t < TOUT; ++t) {
        float4 acc[MROWS];
        #pragma unroll
        for (int m = 0; m < MROWS; ++m) acc[m] = bd;

        for (int j = 0; j < HD; ++j) {
            float4 w = *(const float4*)(WTPd + (j << 10) + (tid << 2));
            const float4* hrow = (const float4*)(hT + j * MROWS);
            float4 h0 = hrow[0], h1 = hrow[1], h2 = hrow[2], h3 = hrow[3];
            FMA4(acc[0],  h0.x, w); FMA4(acc[1],  h0.y, w); FMA4(acc[2],  h0.z, w); FMA4(acc[3],  h0.w, w);
            FMA4(acc[4],  h1.x, w); FMA4(acc[5],  h1.y, w); FMA4(acc[6],  h1.z, w); FMA4(acc[7],  h1.w, w);
            FMA4(acc[8],  h2.x, w); FMA4(acc[9],  h2.y, w); FMA4(acc[10], h2.z, w); FMA4(acc[11], h2.w, w);
            FMA4(acc[12], h3.x, w); FMA4(acc[13], h3.y, w); FMA4(acc[14], h3.z, w); FMA4(acc[15], h3.w, w);
        }
        __syncthreads();
        float hn[MROWS];
        #pragma unroll
        for (int m = 0; m < MROWS; ++m) {
            float iv = sigm(acc[m].x);
            float fv = sigm(acc[m].y);
            float gv = tanh_f(acc[m].z);
            float ov = sigm(acc[m].w);
            float cn = fmaf(fv, c_reg[m], iv * gv);
            c_reg[m] = cn;
            hn[m] = ov * tanh_f(cn);
        }
        {
            float4* dst = (float4*)(hT + tid * MROWS);
            dst[0] = make_float4(hn[0],  hn[1],  hn[2],  hn[3]);
            dst[1] = make_float4(hn[4],  hn[5],  hn[6],  hn[7]);
            dst[2] = make_float4(hn[8],  hn[9],  hn[10], hn[11]);
            dst[3] = make_float4(hn[12], hn[13], hn[14], hn[15]);
        }
        __syncthreads();
        // dense: out[n][o][t] = sum_j hT[j][m] * denseW[t][o][j] + denseb[t][o]
        // threads 0..127: (m,o). Reads of hT race only with next step's
        // pointwise writes, which are ordered behind the next __syncthreads.
        if (tid < MROWS * COUT) {
            int m = tid >> 3, o = tid & 7;
            const float* wr = denseW + t * (COUT * HD) + o * HD;
            float s = denseb[t * COUT + o];
            for (int j = 0; j < HD; ++j)
                s = fmaf(hT[j * MROWS + m], wr[j], s);
            out[(size_t)(n0 + m) * (COUT * TOUT) + o * TOUT + t] = s;
        }
    }
}

extern "C" void kernel_launch(void* const* d_in, const int* in_sizes, int n_in,
                              void* d_out, int out_size, void* d_ws, size_t ws_size,
                              hipStream_t stream) {
    const float* x       = (const float*)d_in[0];
    const float* enc_Wih = (const float*)d_in[1];
    const float* enc_Whh = (const float*)d_in[2];
    const float* enc_b   = (const float*)d_in[3];
    const float* dec_Whh = (const float*)d_in[4];
    const float* dec_b   = (const float*)d_in[5];
    const float* denseW  = (const float*)d_in[6];
    const float* denseb  = (const float*)d_in[7];
    float* out = (float*)d_out;
    float* ws  = (float*)d_ws;

    // 1) permute weights/biases into gate-interleaved transposed layout
    prep_kernel<<<(PREP_TOTAL + 255) / 256, 256, 0, stream>>>(
        enc_Wih, enc_Whh, enc_b, dec_Whh, dec_b, ws);

    // 2) fused recurrence: 512 blocks x 256 threads, 16 batch rows per block
    seq2seq_main<<<NB / MROWS, 256, 0, stream>>>(x, ws, denseW, denseb, out);
}

// Round 2
// 2509.997 us; speedup vs baseline: 1.6337x; 1.6337x over previous
//
#include <hip/hip_runtime.h>

typedef __attribute__((ext_vector_type(8))) _Float16 f16x8;
typedef __attribute__((ext_vector_type(4))) float    f32x4;

#define HD    256
#define CIN   16
#define TIN   48
#define TOUT  24
#define COUT  8
#define MB    32            // batch rows per block
#define KPAD  296           // padded row stride (halves) for hF: 296*2/4 mod 32 = 20 -> 2-way (free)
#define KT_ENC 9            // K = 288 (h 256 | x 16 | pad 16)
#define KT_DEC 8            // K = 256
#define WE_HALVES (KT_ENC*4*16*512)   // 294912
#define WD_HALVES (KT_DEC*4*16*512)   // 262144
#define PREP_TOTAL (WE_HALVES + WD_HALVES)

// Fragment-major fp16 weights: frag id = kt*64 + g*16 + ntile, each frag is
// 64 lanes x 8 halves with b_frag[lane][s] = W[k = kt*32 + (lane>>4)*8 + s]
//                                             [col = g*256 + ntile*16 + (lane&15)]
__global__ void prep_frags(const float* __restrict__ enc_Wih,
                           const float* __restrict__ enc_Whh,
                           const float* __restrict__ dec_Whh,
                           _Float16* __restrict__ wf)
{
    int p = blockIdx.x * blockDim.x + threadIdx.x;
    if (p >= PREP_TOTAL) return;
    int lane = (p >> 3) & 63;
    int s    = p & 7;
    int kq   = ((lane >> 4) << 3) + s;
    int l15  = lane & 15;
    float v;
    if (p < WE_HALVES) {
        int frag = p >> 9;
        int kt = frag >> 6, g = (frag >> 4) & 3, ntile = frag & 15;
        int k   = kt * 32 + kq;
        int row = g * 256 + ntile * 16 + l15;   // gate-row in (4H, *) weight
        v = 0.0f;
        if (k < 256)      v = enc_Whh[row * 256 + k];
        else if (k < 272) v = enc_Wih[row * 16 + (k - 256)];
    } else {
        int q = p - WE_HALVES;
        int frag = q >> 9;
        int kt = frag >> 6, g = (frag >> 4) & 3, ntile = frag & 15;
        int k   = kt * 32 + kq;
        int row = g * 256 + ntile * 16 + l15;
        v = dec_Whh[row * 256 + k];
    }
    wf[p] = (_Float16)v;
}

__device__ __forceinline__ float sigm(float v) {
    return __builtin_amdgcn_rcpf(1.0f + __expf(-v));
}
__device__ __forceinline__ float tanh_f(float v) {
    return 1.0f - 2.0f * __builtin_amdgcn_rcpf(1.0f + __expf(2.0f * v));
}

// grid = 256 blocks (1/CU), 256 threads = 4 waves. Wave w owns unit-columns
// [w*64, w*64+64) for all 4 gates and both 16-row M-tiles. C-state and all 4
// gates stay in registers (C-frag layout: col = lane&15, row = quad*4 + r).
__global__ __launch_bounds__(256, 1) void seq2seq_mfma(
    const float* __restrict__ x,
    const _Float16* __restrict__ wf,
    const float* __restrict__ enc_b,
    const float* __restrict__ dec_b,
    const float* __restrict__ denseW,
    const float* __restrict__ denseb,
    float* __restrict__ out)
{
    __shared__ __align__(16) _Float16 hF[MB * KPAD];   // [m][k] fp16, 18.5 KB

    const int tid  = threadIdx.x;
    const int w    = tid >> 6;
    const int lane = tid & 63;
    const int quad = lane >> 4;
    const int l15  = lane & 15;
    const int n0   = blockIdx.x * MB;

    // biases for this lane's columns, per (gate, ntile)
    float bE[4][4], bD[4][4];
    #pragma unroll
    for (int g = 0; g < 4; ++g)
        #pragma unroll
        for (int nt = 0; nt < 4; ++nt) {
            int col = (w * 4 + nt) * 16 + l15;
            bE[g][nt] = enc_b[g * 256 + col];
            bD[g][nt] = dec_b[g * 256 + col];
        }

    // zero hF (h=0, x slot, pad), then stage x_0
    for (int i = tid; i < MB * KPAD; i += 256) hF[i] = (_Float16)0.0f;
    __syncthreads();
    {
        int m = tid & 31, c0 = (tid >> 5) << 1;
        hF[m * KPAD + 256 + c0]     = (_Float16)x[(n0 + m) * (CIN * TIN) + c0 * TIN];
        hF[m * KPAD + 256 + c0 + 1] = (_Float16)x[(n0 + m) * (CIN * TIN) + (c0 + 1) * TIN];
    }
    __syncthreads();

    f32x4 acc[2][4][4];        // [Mtile][gate][ntile]
    float cst[2][4][4];        // c-state, C-frag layout
    #pragma unroll
    for (int mt = 0; mt < 2; ++mt)
        #pragma unroll
        for (int nt = 0; nt < 4; ++nt)
            #pragma unroll
            for (int r = 0; r < 4; ++r) cst[mt][nt][r] = 0.0f;

    const f16x8* Ap0 = (const f16x8*)(hF + l15 * KPAD);          // Mtile 0
    const f16x8* Ap1 = (const f16x8*)(hF + (16 + l15) * KPAD);   // Mtile 1
    const f16x8* WpE = (const f16x8*)(wf + w * 2048 + lane * 8);
    const f16x8* WpD = (const f16x8*)(wf + WE_HALVES + w * 2048 + lane * 8);

    auto gemm = [&](const f16x8* __restrict__ Wp, const float (&bias)[4][4], int KT) {
        #pragma unroll
        for (int mt = 0; mt < 2; ++mt)
            #pragma unroll
            for (int g = 0; g < 4; ++g)
                #pragma unroll
                for (int nt = 0; nt < 4; ++nt) {
                    float b = bias[g][nt];
                    f32x4 bv = {b, b, b, b};
                    acc[mt][g][nt] = bv;
                }
        #pragma unroll
        for (int kt = 0; kt < KT; ++kt) {
            f16x8 a0 = Ap0[kt * 4 + quad];
            f16x8 a1 = Ap1[kt * 4 + quad];
            #pragma unroll
            for (int g = 0; g < 4; ++g)
                #pragma unroll
                for (int nt = 0; nt < 4; ++nt) {
                    f16x8 bf = Wp[(kt * 64 + g * 16 + nt) * 64];
                    acc[0][g][nt] = __builtin_amdgcn_mfma_f32_16x16x32_f16(a0, bf, acc[0][g][nt], 0, 0, 0);
                    acc[1][g][nt] = __builtin_amdgcn_mfma_f32_16x16x32_f16(a1, bf, acc[1][g][nt], 0, 0, 0);
                }
        }
    };

    auto pointwise = [&]() {
        #pragma unroll
        for (int mt = 0; mt < 2; ++mt)
            #pragma unroll
            for (int nt = 0; nt < 4; ++nt) {
                int col = (w * 4 + nt) * 16 + l15;
                #pragma unroll
                for (int r = 0; r < 4; ++r) {
                    float iv = sigm(acc[mt][0][nt][r]);
                    float fv = sigm(acc[mt][1][nt][r]);
                    float gv = tanh_f(acc[mt][2][nt][r]);
                    float ov = sigm(acc[mt][3][nt][r]);
                    float cn = fmaf(fv, cst[mt][nt][r], iv * gv);
                    cst[mt][nt][r] = cn;
                    float hv = ov * tanh_f(cn);
                    hF[(mt * 16 + quad * 4 + r) * KPAD + col] = (_Float16)hv;
                }
            }
    };

    // ================= encoder =================
    for (int t = 0; t < TIN; ++t) {
        gemm(WpE, bE, KT_ENC);
        __syncthreads();              // all A-frag reads done
        pointwise();                  // write h_t
        if (t + 1 < TIN) {            // stage x_{t+1}
            int m = tid & 31, c0 = (tid >> 5) << 1;
            hF[m * KPAD + 256 + c0]     = (_Float16)x[(n0 + m) * (CIN * TIN) + c0 * TIN + t + 1];
            hF[m * KPAD + 256 + c0 + 1] = (_Float16)x[(n0 + m) * (CIN * TIN) + (c0 + 1) * TIN + t + 1];
        }
        __syncthreads();
    }

    // ================= decoder (c resets to 0) =================
    #pragma unroll
    for (int mt = 0; mt < 2; ++mt)
        #pragma unroll
        for (int nt = 0; nt < 4; ++nt)
            #pragma unroll
            for (int r = 0; r < 4; ++r) cst[mt][nt][r] = 0.0f;

    for (int t = 0; t < TOUT; ++t) {
        gemm(WpD, bD, KT_DEC);
        __syncthreads();
        pointwise();
        __syncthreads();
        // dense epilogue: thread -> (m = tid>>3, o = tid&7); reads h_t from hF
        // (read-only until after next gemm's trailing barrier -> race-free)
        {
            int m = tid >> 3, o = tid & 7;
            const float* wr = denseW + (t * COUT + o) * HD;
            float s = denseb[t * COUT + o];
            #pragma unroll 4
            for (int j8 = 0; j8 < 32; ++j8) {
                f16x8 hv  = *(const f16x8*)(hF + m * KPAD + j8 * 8);
                float4 w0 = *(const float4*)(wr + j8 * 8);
                float4 w1 = *(const float4*)(wr + j8 * 8 + 4);
                s = fmaf((float)hv[0], w0.x, s);
                s = fmaf((float)hv[1], w0.y, s);
                s = fmaf((float)hv[2], w0.z, s);
                s = fmaf((float)hv[3], w0.w, s);
                s = fmaf((float)hv[4], w1.x, s);
                s = fmaf((float)hv[5], w1.y, s);
                s = fmaf((float)hv[6], w1.z, s);
                s = fmaf((float)hv[7], w1.w, s);
            }
            out[(size_t)(n0 + m) * (COUT * TOUT) + o * TOUT + t] = s;
        }
    }
}

extern "C" void kernel_launch(void* const* d_in, const int* in_sizes, int n_in,
                              void* d_out, int out_size, void* d_ws, size_t ws_size,
                              hipStream_t stream) {
    const float* x       = (const float*)d_in[0];
    const float* enc_Wih = (const float*)d_in[1];
    const float* enc_Whh = (const float*)d_in[2];
    const float* enc_b   = (const float*)d_in[3];
    const float* dec_Whh = (const float*)d_in[4];
    const float* dec_b   = (const float*)d_in[5];
    const float* denseW  = (const float*)d_in[6];
    const float* denseb  = (const float*)d_in[7];
    float* out = (float*)d_out;
    _Float16* wf = (_Float16*)d_ws;   // 1.09 MB of fragment-major fp16 weights

    prep_frags<<<(PREP_TOTAL + 255) / 256, 256, 0, stream>>>(enc_Wih, enc_Whh, dec_Whh, wf);
    seq2seq_mfma<<<8192 / MB, 256, 0, stream>>>(x, wf, enc_b, dec_b, denseW, denseb, out);
}

// Round 3
// 1454.144 us; speedup vs baseline: 2.8200x; 1.7261x over previous
//
#include <hip/hip_runtime.h>

typedef __attribute__((ext_vector_type(8))) _Float16 f16x8;
typedef __attribute__((ext_vector_type(4))) float    f32x4;

#define HD    256
#define CIN   16
#define TIN   48
#define TOUT  24
#define COUT  8
#define MB    32            // batch rows per block
#define KPAD  296           // padded row stride (halves) for hF
#define KT_ENC 9            // K = 288 (h 256 | x 16 | pad 16)
#define KT_DEC 8            // K = 256
#define WE_HALVES (KT_ENC*4*16*512)   // 294912
#define WD_HALVES (KT_DEC*4*16*512)   // 262144
#define PREP_TOTAL (WE_HALVES + WD_HALVES)

template <int N> struct KTag { static constexpr int val = N; };

// Fragment-major fp16 weights: frag id = kt*64 + g*16 + ntile, each frag is
// 64 lanes x 8 halves with b_frag[lane][s] = W[k = kt*32 + (lane>>4)*8 + s]
//                                             [col = g*256 + ntile*16 + (lane&15)]
__global__ void prep_frags(const float* __restrict__ enc_Wih,
                           const float* __restrict__ enc_Whh,
                           const float* __restrict__ dec_Whh,
                           _Float16* __restrict__ wf)
{
    int p = blockIdx.x * blockDim.x + threadIdx.x;
    if (p >= PREP_TOTAL) return;
    int lane = (p >> 3) & 63;
    int s    = p & 7;
    int kq   = ((lane >> 4) << 3) + s;
    int l15  = lane & 15;
    float v;
    if (p < WE_HALVES) {
        int frag = p >> 9;
        int kt = frag >> 6, g = (frag >> 4) & 3, ntile = frag & 15;
        int k   = kt * 32 + kq;
        int row = g * 256 + ntile * 16 + l15;
        v = 0.0f;
        if (k < 256)      v = enc_Whh[row * 256 + k];
        else if (k < 272) v = enc_Wih[row * 16 + (k - 256)];
    } else {
        int q = p - WE_HALVES;
        int frag = q >> 9;
        int kt = frag >> 6, g = (frag >> 4) & 3, ntile = frag & 15;
        int k   = kt * 32 + kq;
        int row = g * 256 + ntile * 16 + l15;
        v = dec_Whh[row * 256 + k];
    }
    wf[p] = (_Float16)v;
}

__device__ __forceinline__ float sigm(float v) {
    return __builtin_amdgcn_rcpf(1.0f + __expf(-v));
}
__device__ __forceinline__ float tanh_f(float v) {
    return 1.0f - 2.0f * __builtin_amdgcn_rcpf(1.0f + __expf(2.0f * v));
}

// grid = 256 blocks (1/CU), 512 threads = 8 waves (2/SIMD). Wave w owns unit
// columns [w*32, w*32+32) (ntiles w*2, w*2+1) for all 4 gates, both M-tiles.
__global__ __launch_bounds__(512, 2) void seq2seq_mfma(
    const float* __restrict__ x,
    const _Float16* __restrict__ wf,
    const float* __restrict__ enc_b,
    const float* __restrict__ dec_b,
    const float* __restrict__ denseW,
    const float* __restrict__ denseb,
    float* __restrict__ out)
{
    __shared__ __align__(16) _Float16 hF[MB * KPAD];        // 18.5 KB
    __shared__ __align__(16) _Float16 xs[2][MB * CIN * 8];  // 16 KB, x chunks [m][c][tt]
    __shared__ __align__(16) float    outS[MB * COUT * TOUT]; // 24 KB

    const int tid  = threadIdx.x;
    const int w    = tid >> 6;
    const int lane = tid & 63;
    const int quad = lane >> 4;
    const int l15  = lane & 15;
    const int n0   = blockIdx.x * MB;

    float bE[4][2], bD[4][2];
    #pragma unroll
    for (int g = 0; g < 4; ++g)
        #pragma unroll
        for (int nt = 0; nt < 2; ++nt) {
            int col = (w * 2 + nt) * 16 + l15;
            bE[g][nt] = enc_b[g * 256 + col];
            bD[g][nt] = dec_b[g * 256 + col];
        }

    auto loadchunk = [&](int wd) {   // stage x[:, :, wd*8 .. wd*8+8) -> xs[wd&1]
        int m = tid >> 4, c = tid & 15;
        const float* xp = x + (size_t)(n0 + m) * (CIN * TIN) + c * TIN + wd * 8;
        float4 v0 = *(const float4*)xp;
        float4 v1 = *(const float4*)(xp + 4);
        f16x8 hv = { (_Float16)v0.x, (_Float16)v0.y, (_Float16)v0.z, (_Float16)v0.w,
                     (_Float16)v1.x, (_Float16)v1.y, (_Float16)v1.z, (_Float16)v1.w };
        *(f16x8*)(&xs[wd & 1][m * (CIN * 8) + c * 8]) = hv;
    };
    auto xcopy = [&](int t) {        // xs -> hF x-slot for step t
        int m = tid >> 4, c = tid & 15;
        hF[m * KPAD + 256 + c] = xs[(t >> 3) & 1][m * (CIN * 8) + c * 8 + (t & 7)];
    };

    // zero hF (h=0 and pad), stage chunk 0, place x_0
    for (int i = tid; i < MB * KPAD; i += 512) hF[i] = (_Float16)0.0f;
    loadchunk(0);
    __syncthreads();
    xcopy(0);
    __syncthreads();

    f32x4 acc[2][4][2];        // [Mtile][gate][nt]
    float cst[2][2][4];        // c-state, C-frag layout
    #pragma unroll
    for (int mt = 0; mt < 2; ++mt)
        #pragma unroll
        for (int nt = 0; nt < 2; ++nt)
            #pragma unroll
            for (int r = 0; r < 4; ++r) cst[mt][nt][r] = 0.0f;

    const f16x8* Ap0 = (const f16x8*)(hF + l15 * KPAD);          // Mtile 0
    const f16x8* Ap1 = (const f16x8*)(hF + (16 + l15) * KPAD);   // Mtile 1
    const f16x8* WpE = (const f16x8*)wf + (w * 2) * 64 + lane;
    const f16x8* WpD = (const f16x8*)(wf + WE_HALVES) + (w * 2) * 64 + lane;

    auto gemm = [&](auto kt_tag, const f16x8* __restrict__ Wp, const float (&bias)[4][2]) {
        constexpr int KT = decltype(kt_tag)::val;
        #pragma unroll
        for (int mt = 0; mt < 2; ++mt)
            #pragma unroll
            for (int g = 0; g < 4; ++g)
                #pragma unroll
                for (int nt = 0; nt < 2; ++nt) {
                    float b = bias[g][nt];
                    f32x4 bv = {b, b, b, b};
                    acc[mt][g][nt] = bv;
                }
        #pragma unroll
        for (int kt = 0; kt < KT; ++kt) {
            f16x8 a0 = Ap0[kt * 4 + quad];
            f16x8 a1 = Ap1[kt * 4 + quad];
            #pragma unroll
            for (int g = 0; g < 4; ++g)
                #pragma unroll
                for (int nt = 0; nt < 2; ++nt) {
                    f16x8 bf = Wp[(kt * 64 + g * 16 + nt) * 64];
                    acc[0][g][nt] = __builtin_amdgcn_mfma_f32_16x16x32_f16(a0, bf, acc[0][g][nt], 0, 0, 0);
                    acc[1][g][nt] = __builtin_amdgcn_mfma_f32_16x16x32_f16(a1, bf, acc[1][g][nt], 0, 0, 0);
                }
        }
    };

    auto pointwise = [&]() {
        #pragma unroll
        for (int mt = 0; mt < 2; ++mt)
            #pragma unroll
            for (int nt = 0; nt < 2; ++nt) {
                int col = (w * 2 + nt) * 16 + l15;
                #pragma unroll
                for (int r = 0; r < 4; ++r) {
                    float iv = sigm(acc[mt][0][nt][r]);
                    float fv = sigm(acc[mt][1][nt][r]);
                    float gv = tanh_f(acc[mt][2][nt][r]);
                    float ov = sigm(acc[mt][3][nt][r]);
                    float cn = fmaf(fv, cst[mt][nt][r], iv * gv);
                    cst[mt][nt][r] = cn;
                    float hv = ov * tanh_f(cn);
                    hF[(mt * 16 + quad * 4 + r) * KPAD + col] = (_Float16)hv;
                }
            }
    };

    // ================= encoder =================
    for (int t = 0; t < TIN; ++t) {
        gemm(KTag<KT_ENC>{}, WpE, bE);
        __syncthreads();              // all A-frag reads done
        pointwise();                  // write h_t
        if ((t & 7) == 0 && (t >> 3) + 1 < 6) loadchunk((t >> 3) + 1);
        if (t + 1 < TIN) xcopy(t + 1);
        __syncthreads();
    }

    // ================= decoder (c resets to 0) =================
    #pragma unroll
    for (int mt = 0; mt < 2; ++mt)
        #pragma unroll
        for (int nt = 0; nt < 2; ++nt)
            #pragma unroll
            for (int r = 0; r < 4; ++r) cst[mt][nt][r] = 0.0f;

    for (int t = 0; t < TOUT; ++t) {
        gemm(KTag<KT_DEC>{}, WpD, bD);
        __syncthreads();
        pointwise();
        __syncthreads();
        // dense epilogue -> LDS out buffer (threads 0..255; all reads of hF,
        // next write of hF is behind the next loop's post-gemm barrier)
        if (tid < MB * COUT) {
            int m = tid >> 3, o = tid & 7;
            const float* wr = denseW + (t * COUT + o) * HD;
            float s = denseb[t * COUT + o];
            #pragma unroll 4
            for (int j8 = 0; j8 < 32; ++j8) {
                f16x8 hv  = *(const f16x8*)(hF + m * KPAD + j8 * 8);
                float4 w0 = *(const float4*)(wr + j8 * 8);
                float4 w1 = *(const float4*)(wr + j8 * 8 + 4);
                s = fmaf((float)hv[0], w0.x, s);
                s = fmaf((float)hv[1], w0.y, s);
                s = fmaf((float)hv[2], w0.z, s);
                s = fmaf((float)hv[3], w0.w, s);
                s = fmaf((float)hv[4], w1.x, s);
                s = fmaf((float)hv[5], w1.y, s);
                s = fmaf((float)hv[6], w1.z, s);
                s = fmaf((float)hv[7], w1.w, s);
            }
            outS[m * (COUT * TOUT) + o * TOUT + t] = s;
        }
    }

    // ================= coalesced output flush =================
    __syncthreads();
    {
        const float4* src = (const float4*)outS;
        float4* dst = (float4*)(out + (size_t)n0 * (COUT * TOUT));
        #pragma unroll
        for (int i = 0; i < (MB * COUT * TOUT / 4) / 512; ++i)
            dst[tid + i * 512] = src[tid + i * 512];
    }
}

extern "C" void kernel_launch(void* const* d_in, const int* in_sizes, int n_in,
                              void* d_out, int out_size, void* d_ws, size_t ws_size,
                              hipStream_t stream) {
    const float* x       = (const float*)d_in[0];
    const float* enc_Wih = (const float*)d_in[1];
    const float* enc_Whh = (const float*)d_in[2];
    const float* enc_b   = (const float*)d_in[3];
    const float* dec_Whh = (const float*)d_in[4];
    const float* dec_b   = (const float*)d_in[5];
    const float* denseW  = (const float*)d_in[6];
    const float* denseb  = (const float*)d_in[7];
    float* out = (float*)d_out;
    _Float16* wf = (_Float16*)d_ws;   // 1.09 MB fragment-major fp16 weights

    prep_frags<<<(PREP_TOTAL + 255) / 256, 256, 0, stream>>>(enc_Wih, enc_Whh, dec_Whh, wf);
    seq2seq_mfma<<<8192 / MB, 512, 0, stream>>>(x, wf, enc_b, dec_b, denseW, denseb, out);
}

// Round 4
// 1393.118 us; speedup vs baseline: 2.9435x; 1.0438x over previous
//
#include <hip/hip_runtime.h>

typedef __attribute__((ext_vector_type(8))) _Float16 f16x8;
typedef __attribute__((ext_vector_type(4))) float    f32x4;

#define HD    256
#define CIN   16
#define TIN   48
#define TOUT  24
#define COUT  8
#define MB    32            // batch rows per block
#define KPAD  296           // padded row stride (halves) for hF
#define KT_ENC 9            // K = 288 (h 256 | x 16 | pad 16)
#define KT_DEC 8            // K = 256
#define WE_HALVES (KT_ENC*4*16*512)   // 294912
#define WD_HALVES (KT_DEC*4*16*512)   // 262144
#define PREP_TOTAL (WE_HALVES + WD_HALVES)

template <int N> struct KTag { static constexpr int val = N; };

// Fragment-major fp16 weights: frag id = kt*64 + g*16 + ntile, each frag is
// 64 lanes x 8 halves with b_frag[lane][s] = W[k = kt*32 + (lane>>4)*8 + s]
//                                             [col = g*256 + ntile*16 + (lane&15)]
__global__ void prep_frags(const float* __restrict__ enc_Wih,
                           const float* __restrict__ enc_Whh,
                           const float* __restrict__ dec_Whh,
                           _Float16* __restrict__ wf)
{
    int p = blockIdx.x * blockDim.x + threadIdx.x;
    if (p >= PREP_TOTAL) return;
    int lane = (p >> 3) & 63;
    int s    = p & 7;
    int kq   = ((lane >> 4) << 3) + s;
    int l15  = lane & 15;
    float v;
    if (p < WE_HALVES) {
        int frag = p >> 9;
        int kt = frag >> 6, g = (frag >> 4) & 3, ntile = frag & 15;
        int k   = kt * 32 + kq;
        int row = g * 256 + ntile * 16 + l15;
        v = 0.0f;
        if (k < 256)      v = enc_Whh[row * 256 + k];
        else if (k < 272) v = enc_Wih[row * 16 + (k - 256)];
    } else {
        int q = p - WE_HALVES;
        int frag = q >> 9;
        int kt = frag >> 6, g = (frag >> 4) & 3, ntile = frag & 15;
        int k   = kt * 32 + kq;
        int row = g * 256 + ntile * 16 + l15;
        v = dec_Whh[row * 256 + k];
    }
    wf[p] = (_Float16)v;
}

__device__ __forceinline__ float sigm(float v) {
    return __builtin_amdgcn_rcpf(1.0f + __expf(-v));
}
__device__ __forceinline__ float tanh_f(float v) {
    return 1.0f - 2.0f * __builtin_amdgcn_rcpf(1.0f + __expf(2.0f * v));
}

// grid = 256 blocks (1/CU), 1024 threads = 16 waves (4/SIMD). Wave w owns
// ntile w: unit-columns [w*16, w*16+16) for all 4 gates, both 16-row M-tiles.
// acc = 4 gates x 2 mt x f32x4 = 32 VGPRs -> fits the 128-VGPR/4-wave budget.
__global__ __launch_bounds__(1024, 4) void seq2seq_mfma(
    const float* __restrict__ x,
    const _Float16* __restrict__ wf,
    const float* __restrict__ enc_b,
    const float* __restrict__ dec_b,
    const float* __restrict__ denseW,
    const float* __restrict__ denseb,
    float* __restrict__ out)
{
    __shared__ __align__(16) _Float16 hF[MB * KPAD];          // 18.5 KB
    __shared__ __align__(16) _Float16 xs[2][MB * CIN * 8];    // 16 KB
    __shared__ __align__(16) float    outS[MB * COUT * TOUT]; // 24 KB

    const int tid  = threadIdx.x;
    const int w    = tid >> 6;       // 0..15 = ntile
    const int lane = tid & 63;
    const int quad = lane >> 4;
    const int l15  = lane & 15;
    const int n0   = blockIdx.x * MB;

    float bE[4], bD[4];
    #pragma unroll
    for (int g = 0; g < 4; ++g) {
        int col = w * 16 + l15;
        bE[g] = enc_b[g * 256 + col];
        bD[g] = dec_b[g * 256 + col];
    }

    auto loadchunk = [&](int wd) {   // stage x[:, :, wd*8 .. wd*8+8) -> xs[wd&1]
        if (tid < 512) {
            int m = tid >> 4, c = tid & 15;
            const float* xp = x + (size_t)(n0 + m) * (CIN * TIN) + c * TIN + wd * 8;
            float4 v0 = *(const float4*)xp;
            float4 v1 = *(const float4*)(xp + 4);
            f16x8 hv = { (_Float16)v0.x, (_Float16)v0.y, (_Float16)v0.z, (_Float16)v0.w,
                         (_Float16)v1.x, (_Float16)v1.y, (_Float16)v1.z, (_Float16)v1.w };
            *(f16x8*)(&xs[wd & 1][m * (CIN * 8) + c * 8]) = hv;
        }
    };
    auto xcopy = [&](int t) {        // xs -> hF x-slot for step t
        if (tid < 512) {
            int m = tid >> 4, c = tid & 15;
            hF[m * KPAD + 256 + c] = xs[(t >> 3) & 1][m * (CIN * 8) + c * 8 + (t & 7)];
        }
    };

    for (int i = tid; i < MB * KPAD; i += 1024) hF[i] = (_Float16)0.0f;
    loadchunk(0);
    __syncthreads();
    xcopy(0);
    __syncthreads();

    f32x4 acc[2][4];        // [Mtile][gate]
    float cst[2][4];        // c-state, C-frag layout rows
    #pragma unroll
    for (int mt = 0; mt < 2; ++mt)
        #pragma unroll
        for (int r = 0; r < 4; ++r) cst[mt][r] = 0.0f;

    const f16x8* Ap0 = (const f16x8*)(hF + l15 * KPAD);          // Mtile 0
    const f16x8* Ap1 = (const f16x8*)(hF + (16 + l15) * KPAD);   // Mtile 1
    const f16x8* WpE = (const f16x8*)wf + w * 64 + lane;
    const f16x8* WpD = (const f16x8*)(wf + WE_HALVES) + w * 64 + lane;

    auto gemm = [&](auto kt_tag, const f16x8* __restrict__ Wp, const float (&bias)[4]) {
        constexpr int KT = decltype(kt_tag)::val;
        #pragma unroll
        for (int mt = 0; mt < 2; ++mt)
            #pragma unroll
            for (int g = 0; g < 4; ++g) {
                float b = bias[g];
                f32x4 bv = {b, b, b, b};
                acc[mt][g] = bv;
            }
        #pragma unroll
        for (int kt = 0; kt < KT; ++kt) {
            f16x8 a0 = Ap0[kt * 4 + quad];
            f16x8 a1 = Ap1[kt * 4 + quad];
            #pragma unroll
            for (int g = 0; g < 4; ++g) {
                f16x8 bf = Wp[(kt * 4 + g) * 1024];   // frag (kt*64 + g*16 + w)
                acc[0][g] = __builtin_amdgcn_mfma_f32_16x16x32_f16(a0, bf, acc[0][g], 0, 0, 0);
                acc[1][g] = __builtin_amdgcn_mfma_f32_16x16x32_f16(a1, bf, acc[1][g], 0, 0, 0);
            }
        }
    };

    auto pointwise = [&]() {
        int col = w * 16 + l15;
        #pragma unroll
        for (int mt = 0; mt < 2; ++mt)
            #pragma unroll
            for (int r = 0; r < 4; ++r) {
                float iv = sigm(acc[mt][0][r]);
                float fv = sigm(acc[mt][1][r]);
                float gv = tanh_f(acc[mt][2][r]);
                float ov = sigm(acc[mt][3][r]);
                float cn = fmaf(fv, cst[mt][r], iv * gv);
                cst[mt][r] = cn;
                float hv = ov * tanh_f(cn);
                hF[(mt * 16 + quad * 4 + r) * KPAD + col] = (_Float16)hv;
            }
    };

    // ================= encoder =================
    for (int t = 0; t < TIN; ++t) {
        gemm(KTag<KT_ENC>{}, WpE, bE);
        __syncthreads();              // all A-frag reads done
        pointwise();                  // write h_t
        if ((t & 7) == 0 && (t >> 3) + 1 < 6) loadchunk((t >> 3) + 1);
        if (t + 1 < TIN) xcopy(t + 1);
        __syncthreads();
    }

    // ================= decoder (c resets to 0) =================
    #pragma unroll
    for (int mt = 0; mt < 2; ++mt)
        #pragma unroll
        for (int r = 0; r < 4; ++r) cst[mt][r] = 0.0f;

    for (int t = 0; t < TOUT; ++t) {
        gemm(KTag<KT_DEC>{}, WpD, bD);
        __syncthreads();
        pointwise();
        __syncthreads();
        // dense epilogue -> LDS out buffer (threads 0..255). hF is read-only
        // until the next step's post-gemm barrier -> race-free.
        if (tid < MB * COUT) {
            int m = tid >> 3, o = tid & 7;
            const float* wr = denseW + (t * COUT + o) * HD;
            float s = denseb[t * COUT + o];
            #pragma unroll 4
            for (int j8 = 0; j8 < 32; ++j8) {
                f16x8 hv  = *(const f16x8*)(hF + m * KPAD + j8 * 8);
                float4 w0 = *(const float4*)(wr + j8 * 8);
                float4 w1 = *(const float4*)(wr + j8 * 8 + 4);
                s = fmaf((float)hv[0], w0.x, s);
                s = fmaf((float)hv[1], w0.y, s);
                s = fmaf((float)hv[2], w0.z, s);
                s = fmaf((float)hv[3], w0.w, s);
                s = fmaf((float)hv[4], w1.x, s);
                s = fmaf((float)hv[5], w1.y, s);
                s = fmaf((float)hv[6], w1.z, s);
                s = fmaf((float)hv[7], w1.w, s);
            }
            outS[m * (COUT * TOUT) + o * TOUT + t] = s;
        }
    }

    // ================= coalesced output flush =================
    __syncthreads();
    {
        const float4* src = (const float4*)outS;
        float4* dst = (float4*)(out + (size_t)n0 * (COUT * TOUT));
        for (int i = tid; i < MB * COUT * TOUT / 4; i += 1024)
            dst[i] = src[i];
    }
}

extern "C" void kernel_launch(void* const* d_in, const int* in_sizes, int n_in,
                              void* d_out, int out_size, void* d_ws, size_t ws_size,
                              hipStream_t stream) {
    const float* x       = (const float*)d_in[0];
    const float* enc_Wih = (const float*)d_in[1];
    const float* enc_Whh = (const float*)d_in[2];
    const float* enc_b   = (const float*)d_in[3];
    const float* dec_Whh = (const float*)d_in[4];
    const float* dec_b   = (const float*)d_in[5];
    const float* denseW  = (const float*)d_in[6];
    const float* denseb  = (const float*)d_in[7];
    float* out = (float*)d_out;
    _Float16* wf = (_Float16*)d_ws;   // 1.09 MB fragment-major fp16 weights

    prep_frags<<<(PREP_TOTAL + 255) / 256, 256, 0, stream>>>(enc_Wih, enc_Whh, dec_Whh, wf);
    seq2seq_mfma<<<8192 / MB, 1024, 0, stream>>>(x, wf, enc_b, dec_b, denseW, denseb, out);
}